// Round 9
// baseline (1832.442 us; speedup 1.0000x reference)
//
#include <hip/hip_runtime.h>
#include <hip/hip_bf16.h>
#include <math.h>

typedef __hip_bfloat16 bf16;
typedef __attribute__((ext_vector_type(8))) short short8;   // 8 bf16 (4 VGPRs)
typedef __attribute__((ext_vector_type(4))) float floatx4;  // 4 fp32 acc

#define B_  32
#define H_  168
#define N_  512
#define P_  24
#define NF_ 4096
#define G4N 2048
#define M1  (B_*H_)        // 5376
#define NX  (M1*NF_)       // 22020096
#define TSTEPS (H_+P_)     // 192
#define NWG 64
#define HSZ (B_*N_)        // one h buffer: 16384 bf16 = 32 KB

// ---------------- fp32 -> bf16 convert (x) ----------------------------------
__global__ __launch_bounds__(256) void cvt_f32_bf16(const float* __restrict__ in,
                                                    bf16* __restrict__ out, int n4) {
  int i = blockIdx.x * 256 + threadIdx.x;
  if (i < n4) {
    float4 v = ((const float4*)in)[i];
    bf16 o[4] = {__float2bfloat16(v.x), __float2bfloat16(v.y),
                 __float2bfloat16(v.z), __float2bfloat16(v.w)};
    *(ulong1*)(out + (size_t)i * 4) = *(ulong1*)o;
  }
}

// ---------- tiled transpose + convert: out[C,R](bf16) = in[R,C](f32)^T ------
__global__ __launch_bounds__(256) void transpose_cvt(const float* __restrict__ in,
                                                     bf16* __restrict__ out,
                                                     int R, int C) {
  __shared__ float t[32][33];
  int bx = blockIdx.x, by = blockIdx.y;
  int tx = threadIdx.x, ty = threadIdx.y;
#pragma unroll
  for (int yy = 0; yy < 32; yy += 8)
    t[ty + yy][tx] = in[(size_t)(by * 32 + ty + yy) * C + bx * 32 + tx];
  __syncthreads();
#pragma unroll
  for (int yy = 0; yy < 32; yy += 8)
    out[(size_t)(bx * 32 + ty + yy) * R + by * 32 + tx] =
        __float2bfloat16(t[tx][ty + yy]);
}

// ---- fused transpose of lstm_k / lstm_rk -> kT, rkT, wcT=(k+rk)^T ----------
__global__ __launch_bounds__(256) void transpose_krk(const float* __restrict__ k,
                                                     const float* __restrict__ rk,
                                                     bf16* __restrict__ kT,
                                                     bf16* __restrict__ rkT,
                                                     bf16* __restrict__ wcT) {
  __shared__ float t1[32][33], t2[32][33];
  int bx = blockIdx.x, by = blockIdx.y;
  int tx = threadIdx.x, ty = threadIdx.y;
#pragma unroll
  for (int yy = 0; yy < 32; yy += 8) {
    size_t idx = (size_t)(by * 32 + ty + yy) * G4N + bx * 32 + tx;
    t1[ty + yy][tx] = k[idx];
    t2[ty + yy][tx] = rk[idx];
  }
  __syncthreads();
#pragma unroll
  for (int yy = 0; yy < 32; yy += 8) {
    size_t o = (size_t)(bx * 32 + ty + yy) * N_ + by * 32 + tx;
    float a = t1[tx][ty + yy], b = t2[tx][ty + yy];
    kT[o]  = __float2bfloat16(a);
    rkT[o] = __float2bfloat16(b);
    wcT[o] = __float2bfloat16(a + b);
  }
}

// ---------------- C[M,N] = A[M,K] @ BT[N,K]^T (+bias) -----------------------
template <bool OUT_BF16>
__global__ __launch_bounds__(256) void gemm_bt(const bf16* __restrict__ A,
                                               const bf16* __restrict__ BT,
                                               const float* __restrict__ bias,
                                               void* __restrict__ Cout,
                                               int M, int N, int K, int permute) {
  __shared__ short As[128 * 40];
  __shared__ short Bs[128 * 40];
  int tid  = threadIdx.x;
  int wave = tid >> 6, lane = tid & 63;
  int wm = wave >> 1, wn = wave & 1;
  int quad = lane >> 4, l16 = lane & 15;
  int m0 = blockIdx.y * 128, n0 = blockIdx.x * 128;

  floatx4 acc[4][4];
#pragma unroll
  for (int i = 0; i < 4; i++)
#pragma unroll
    for (int j = 0; j < 4; j++) acc[i][j] = (floatx4){0.f, 0.f, 0.f, 0.f};

  int r0 = tid >> 2;
  int c0 = (tid & 3) * 8;

  for (int k0 = 0; k0 < K; k0 += 32) {
    short8 a0 = *(const short8*)(A  + (size_t)(m0 + r0)      * K + k0 + c0);
    short8 a1 = *(const short8*)(A  + (size_t)(m0 + r0 + 64) * K + k0 + c0);
    short8 b0 = *(const short8*)(BT + (size_t)(n0 + r0)      * K + k0 + c0);
    short8 b1 = *(const short8*)(BT + (size_t)(n0 + r0 + 64) * K + k0 + c0);
    __syncthreads();
    *(short8*)(&As[r0 * 40 + c0])        = a0;
    *(short8*)(&As[(r0 + 64) * 40 + c0]) = a1;
    *(short8*)(&Bs[r0 * 40 + c0])        = b0;
    *(short8*)(&Bs[(r0 + 64) * 40 + c0]) = b1;
    __syncthreads();
    short8 af[4], bfr[4];
#pragma unroll
    for (int i = 0; i < 4; i++)
      af[i] = *(const short8*)(&As[(wm * 64 + i * 16 + l16) * 40 + quad * 8]);
#pragma unroll
    for (int j = 0; j < 4; j++)
      bfr[j] = *(const short8*)(&Bs[(wn * 64 + j * 16 + l16) * 40 + quad * 8]);
#pragma unroll
    for (int i = 0; i < 4; i++)
#pragma unroll
      for (int j = 0; j < 4; j++)
        acc[i][j] = __builtin_amdgcn_mfma_f32_16x16x32_bf16(af[i], bfr[j],
                                                            acc[i][j], 0, 0, 0);
  }
#pragma unroll
  for (int i = 0; i < 4; i++) {
    int row = m0 + wm * 64 + i * 16 + quad * 4;
#pragma unroll
    for (int j = 0; j < 4; j++) {
      int col = n0 + wn * 64 + j * 16 + l16;
      float bv = bias ? bias[col] : 0.f;
#pragma unroll
      for (int r = 0; r < 4; r++) {
        int gr = row + r;
        int orow = permute ? (gr % H_) * B_ + gr / H_ : gr;
        float v = acc[i][j][r] + bv;
        if (OUT_BF16)
          ((bf16*)Cout)[(size_t)orow * N + col] = __float2bfloat16(v);
        else
          ((float*)Cout)[(size_t)orow * N + col] = v;
      }
    }
  }
}

// ---------------- persistent LSTM recurrence, DATAFLOW (no barrier) ---------
// 64 WGs x 256 thr. WG g owns n in [g*8,g*8+8) -> 32 gate cols {gate*512+n}.
// Weights LDS-resident, c in registers. h ring: one fresh 32KB buffer per
// step, pre-filled with 0xFF bytes (bf16 0xFFFF = NaN sentinel; real h is
// always finite). Producers fire relaxed agent-scope 8B stores; each
// consumer lane polls ITS OWN fragment words (agent-scope = L2-bypass,
// required: a cached poll would spin on a stale line) until no word holds
// an 0xFFFF short. The data is the sync signal: one L3 hop per step.
__global__ __launch_bounds__(256) void lstm_persist(
    const bf16* __restrict__ rkT,   // [2048,512] recurrent (encoder)
    const bf16* __restrict__ wcT,   // [2048,512] k+rk (decoder)
    const float* __restrict__ bvec, // [2048]
    const float* __restrict__ xk,   // [H*B, 2048] fp32, rows t*B+b
    bf16* __restrict__ hring,       // [(TSTEPS+1)*B*N]; [0] zeroed, rest 0xFF
    bf16* __restrict__ preds) {     // [B,P,N]
  __shared__ short Wenc[32][520];
  __shared__ short Wdec[32][520];
  __shared__ float zs[32][33];
  __shared__ bf16  hstage[32][8];

  int tid  = threadIdx.x;
  int bid  = blockIdx.x;
  int wave = tid >> 6, lane = tid & 63;
  int tm = wave >> 1, tn = wave & 1;
  int quad = lane >> 4, l16 = lane & 15;
  int n0 = bid * 8;
  int lc   = tn * 16 + l16;                     // local col 0..31
  int gcol = ((lc >> 3) << 9) + n0 + (lc & 7);  // gate*512 + n
  int brow = tm * 16 + quad * 4;

  for (int idx = tid; idx < 32 * 64; idx += 256) {
    int r = idx >> 6, ck = (idx & 63) << 3;
    int grow = ((r >> 3) << 9) + n0 + (r & 7);
    *(short8*)&Wenc[r][ck] = *(const short8*)(rkT + (size_t)grow * 512 + ck);
    *(short8*)&Wdec[r][ck] = *(const short8*)(wcT + (size_t)grow * 512 + ck);
  }
  float bias_r = bvec[gcol];
  int b = tid >> 3, j = tid & 7;
  int nn = n0 + j;
  float c_reg = 0.f;

  // prefetch xk for t=0
  float xkv[4];
  {
    const float* xp = xk + (size_t)brow * G4N + gcol;
#pragma unroll
    for (int r = 0; r < 4; ++r) xkv[r] = xp[(size_t)r * G4N];
  }
  __syncthreads();

  const unsigned long long K1 = 0x0001000100010001ULL;
  const unsigned long long K8 = 0x8000800080010000ULL & 0x8000800080008000ULL; // 0x8000...
  const unsigned long long KH = 0x8000800080008000ULL;

  for (int t = 0; t < TSTEPS; ++t) {
    const bf16* h_in  = hring + (size_t)t * HSZ;
    bf16*       h_out = hring + (size_t)(t + 1) * HSZ;
    const short(*Ws)[520] = (t < H_) ? Wenc : Wdec;

    // ---- dataflow poll: this lane's A-fragment = row (tm*16+l16), shorts
    // [c*32+quad*8, +8) for c in 0..16 -> 32 x 8B words. Valid when no short
    // equals 0xFFFF (~v has a zero short; exact zero-short detect).
    unsigned long long w[32];
    {
      const unsigned long long* hp =
          (const unsigned long long*)(h_in + (size_t)(tm * 16 + l16) * 512) +
          quad * 2;
      for (;;) {
        unsigned long long bad = 0;
#pragma unroll
        for (int c = 0; c < 16; ++c) {
#pragma unroll
          for (int e = 0; e < 2; ++e) {
            unsigned long long v = __hip_atomic_load(
                hp + c * 8 + e, __ATOMIC_RELAXED, __HIP_MEMORY_SCOPE_AGENT);
            w[c * 2 + e] = v;
            unsigned long long nv = ~v;
            bad |= (nv - K1) & v & KH;  // nonzero iff some short of v==0xFFFF
          }
        }
        if (__ballot(bad != 0) == 0) break;
        __builtin_amdgcn_s_sleep(1);
      }
    }

    // ---- MFMA from polled registers ----
    floatx4 acc0 = (floatx4){0.f, 0.f, 0.f, 0.f};
    floatx4 acc1 = (floatx4){0.f, 0.f, 0.f, 0.f};
#pragma unroll
    for (int c = 0; c < 16; c += 2) {
      union { unsigned long long u[2]; short8 s; } a0, a1;
      a0.u[0] = w[c * 2];     a0.u[1] = w[c * 2 + 1];
      a1.u[0] = w[c * 2 + 2]; a1.u[1] = w[c * 2 + 3];
      short8 b0 = *(const short8*)&Ws[lc][c * 32 + quad * 8];
      short8 b1 = *(const short8*)&Ws[lc][(c + 1) * 32 + quad * 8];
      acc0 = __builtin_amdgcn_mfma_f32_16x16x32_bf16(a0.s, b0, acc0, 0, 0, 0);
      acc1 = __builtin_amdgcn_mfma_f32_16x16x32_bf16(a1.s, b1, acc1, 0, 0, 0);
    }
    floatx4 acc = acc0 + acc1;
#pragma unroll
    for (int r = 0; r < 4; ++r)
      zs[brow + r][lc] = acc[r] + bias_r + xkv[r];

    // prefetch next step's xk (read-only, cached; consumed next iter)
    float xn[4] = {0.f, 0.f, 0.f, 0.f};
    if (t + 1 < H_) {
      const float* xp = xk + (size_t)((t + 1) * B_ + brow) * G4N + gcol;
#pragma unroll
      for (int r = 0; r < 4; ++r) xn[r] = xp[(size_t)r * G4N];
    }
    __syncthreads();

    // ---- gates ----
    float zi = zs[b][j], zf = zs[b][8 + j], zg = zs[b][16 + j], zo = zs[b][24 + j];
    float ig = 1.f / (1.f + __expf(-zi));
    float fg = 1.f / (1.f + __expf(-zf));
    float gg = tanhf(zg);
    float og = 1.f / (1.f + __expf(-zo));
    c_reg = fg * c_reg + ig * gg;
    float hn = og * tanhf(c_reg);
    hstage[b][j] = __float2bfloat16(hn);
    if (t >= H_)
      preds[(size_t)b * (P_ * N_) + (t - H_) * N_ + nn] = __float2bfloat16(hn);
    __syncthreads();

    // ---- fire h_out: 64 threads x 8B relaxed agent stores (no ack wait) ----
    if (tid < 64) {
      int bb = tid >> 1, f4 = (tid & 1) * 4;
      unsigned long long v = *(const unsigned long long*)&hstage[bb][f4];
      __hip_atomic_store((unsigned long long*)(h_out + bb * 512 + n0 + f4), v,
                         __ATOMIC_RELAXED, __HIP_MEMORY_SCOPE_AGENT);
    }
#pragma unroll
    for (int r = 0; r < 4; ++r) xkv[r] = xn[r];
  }
}

extern "C" void kernel_launch(void* const* d_in, const int* in_sizes, int n_in,
                              void* d_out, int out_size, void* d_ws, size_t ws_size,
                              hipStream_t stream) {
  const float* x       = (const float*)d_in[0];
  const float* conv_w  = (const float*)d_in[1];
  const float* conv_b  = (const float*)d_in[2];
  const float* lstm_k  = (const float*)d_in[3];
  const float* lstm_rk = (const float*)d_in[4];
  const float* lstm_b  = (const float*)d_in[5];
  const float* dense_w = (const float*)d_in[6];
  const float* dense_b = (const float*)d_in[7];
  float* out = (float*)d_out;

  char* p = (char*)d_ws;
  auto carve = [&](size_t bytes) {
    char* r = p;
    p += (bytes + 255) & ~(size_t)255;
    return r;
  };
  bf16*  xb    = (bf16*)carve((size_t)NX * 2);
  bf16*  xr    = (bf16*)carve((size_t)M1 * N_ * 2);    // rows t*B+b
  float* xk    = (float*)carve((size_t)M1 * G4N * 4);  // rows t*B+b
  bf16*  cwT   = (bf16*)carve((size_t)N_ * NF_ * 2);
  bf16*  kT    = (bf16*)carve((size_t)G4N * N_ * 2);
  bf16*  rkT   = (bf16*)carve((size_t)G4N * N_ * 2);
  bf16*  wcT   = (bf16*)carve((size_t)G4N * N_ * 2);
  bf16*  dwT   = (bf16*)carve((size_t)N_ * N_ * 2);
  bf16*  preds = (bf16*)carve((size_t)B_ * P_ * N_ * 2);
  bf16*  hring = (bf16*)carve((size_t)(TSTEPS + 1) * HSZ * 2);  // 6.3 MB

  cvt_f32_bf16<<<(NX / 4 + 255) / 256, 256, 0, stream>>>(x, xb, NX / 4);
  dim3 tb(32, 8);
  transpose_cvt<<<dim3(N_ / 32, NF_ / 32), tb, 0, stream>>>(conv_w, cwT, NF_, N_);
  transpose_krk<<<dim3(G4N / 32, N_ / 32), tb, 0, stream>>>(lstm_k, lstm_rk,
                                                            kT, rkT, wcT);
  transpose_cvt<<<dim3(N_ / 32, N_ / 32), tb, 0, stream>>>(dense_w, dwT, N_, N_);
  // sentinel-fill the whole ring (0xFF bytes = bf16 NaN), then zero h[0]
  hipMemsetAsync(hring, 0xFF, (size_t)(TSTEPS + 1) * HSZ * 2, stream);
  hipMemsetAsync(hring, 0, (size_t)HSZ * 2, stream);

  // xr = x @ conv_w + conv_b, rows permuted (b*H+t) -> (t*B+b)
  gemm_bt<true><<<dim3(N_ / 128, M1 / 128), 256, 0, stream>>>(xb, cwT, conv_b, xr,
                                                              M1, N_, NF_, 1);
  // xk = xr @ lstm_k -> fp32 (row order preserved: t*B+b)
  gemm_bt<false><<<dim3(G4N / 128, M1 / 128), 256, 0, stream>>>(xr, kT, nullptr,
                                                                xk, M1, G4N, N_, 0);

  lstm_persist<<<NWG, 256, 0, stream>>>(rkT, wcT, lstm_b, xk, hring, preds);

  // out = preds @ dense_w + dense_b
  gemm_bt<false><<<dim3(N_ / 128, (B_ * P_) / 128), 256, 0, stream>>>(
      preds, dwT, dense_b, out, B_ * P_, N_, N_, 0);
}

// Round 10
// 1116.817 us; speedup vs baseline: 1.6408x; 1.6408x over previous
//
#include <hip/hip_runtime.h>
#include <hip/hip_bf16.h>
#include <math.h>

typedef __hip_bfloat16 bf16;
typedef __attribute__((ext_vector_type(8))) short short8;   // 8 bf16 (4 VGPRs)
typedef __attribute__((ext_vector_type(4))) float floatx4;  // 4 fp32 acc

#define B_  32
#define H_  168
#define N_  512
#define P_  24
#define NF_ 4096
#define G4N 2048
#define M1  (B_*H_)        // 5376
#define TSTEPS (H_+P_)     // 192
#define NWG 64
#define HSZ (B_*N_)        // one h buffer: 16384 bf16 = 32 KB

// ---------- tiled transpose + convert: out[C,R](bf16) = in[R,C](f32)^T ------
__global__ __launch_bounds__(256) void transpose_cvt(const float* __restrict__ in,
                                                     bf16* __restrict__ out,
                                                     int R, int C) {
  __shared__ float t[32][33];
  int bx = blockIdx.x, by = blockIdx.y;
  int tx = threadIdx.x, ty = threadIdx.y;
#pragma unroll
  for (int yy = 0; yy < 32; yy += 8)
    t[ty + yy][tx] = in[(size_t)(by * 32 + ty + yy) * C + bx * 32 + tx];
  __syncthreads();
#pragma unroll
  for (int yy = 0; yy < 32; yy += 8)
    out[(size_t)(bx * 32 + ty + yy) * R + by * 32 + tx] =
        __float2bfloat16(t[tx][ty + yy]);
}

// ---- fused transpose of lstm_k / lstm_rk -> kT, rkT, wcT=(k+rk)^T ----------
__global__ __launch_bounds__(256) void transpose_krk(const float* __restrict__ k,
                                                     const float* __restrict__ rk,
                                                     bf16* __restrict__ kT,
                                                     bf16* __restrict__ rkT,
                                                     bf16* __restrict__ wcT) {
  __shared__ float t1[32][33], t2[32][33];
  int bx = blockIdx.x, by = blockIdx.y;
  int tx = threadIdx.x, ty = threadIdx.y;
#pragma unroll
  for (int yy = 0; yy < 32; yy += 8) {
    size_t idx = (size_t)(by * 32 + ty + yy) * G4N + bx * 32 + tx;
    t1[ty + yy][tx] = k[idx];
    t2[ty + yy][tx] = rk[idx];
  }
  __syncthreads();
#pragma unroll
  for (int yy = 0; yy < 32; yy += 8) {
    size_t o = (size_t)(bx * 32 + ty + yy) * N_ + by * 32 + tx;
    float a = t1[tx][ty + yy], b = t2[tx][ty + yy];
    kT[o]  = __float2bfloat16(a);
    rkT[o] = __float2bfloat16(b);
    wcT[o] = __float2bfloat16(a + b);
  }
}

// ---------------- C[M,N] = A[M,K] @ BT[N,K]^T (+bias) -----------------------
template <bool OUT_BF16>
__global__ __launch_bounds__(256) void gemm_bt(const bf16* __restrict__ A,
                                               const bf16* __restrict__ BT,
                                               const float* __restrict__ bias,
                                               void* __restrict__ Cout,
                                               int M, int N, int K, int permute) {
  __shared__ short As[128 * 40];
  __shared__ short Bs[128 * 40];
  int tid  = threadIdx.x;
  int wave = tid >> 6, lane = tid & 63;
  int wm = wave >> 1, wn = wave & 1;
  int quad = lane >> 4, l16 = lane & 15;
  int m0 = blockIdx.y * 128, n0 = blockIdx.x * 128;

  floatx4 acc[4][4];
#pragma unroll
  for (int i = 0; i < 4; i++)
#pragma unroll
    for (int j = 0; j < 4; j++) acc[i][j] = (floatx4){0.f, 0.f, 0.f, 0.f};

  int r0 = tid >> 2;
  int c0 = (tid & 3) * 8;

  for (int k0 = 0; k0 < K; k0 += 32) {
    short8 a0 = *(const short8*)(A  + (size_t)(m0 + r0)      * K + k0 + c0);
    short8 a1 = *(const short8*)(A  + (size_t)(m0 + r0 + 64) * K + k0 + c0);
    short8 b0 = *(const short8*)(BT + (size_t)(n0 + r0)      * K + k0 + c0);
    short8 b1 = *(const short8*)(BT + (size_t)(n0 + r0 + 64) * K + k0 + c0);
    __syncthreads();
    *(short8*)(&As[r0 * 40 + c0])        = a0;
    *(short8*)(&As[(r0 + 64) * 40 + c0]) = a1;
    *(short8*)(&Bs[r0 * 40 + c0])        = b0;
    *(short8*)(&Bs[(r0 + 64) * 40 + c0]) = b1;
    __syncthreads();
    short8 af[4], bfr[4];
#pragma unroll
    for (int i = 0; i < 4; i++)
      af[i] = *(const short8*)(&As[(wm * 64 + i * 16 + l16) * 40 + quad * 8]);
#pragma unroll
    for (int j = 0; j < 4; j++)
      bfr[j] = *(const short8*)(&Bs[(wn * 64 + j * 16 + l16) * 40 + quad * 8]);
#pragma unroll
    for (int i = 0; i < 4; i++)
#pragma unroll
      for (int j = 0; j < 4; j++)
        acc[i][j] = __builtin_amdgcn_mfma_f32_16x16x32_bf16(af[i], bfr[j],
                                                            acc[i][j], 0, 0, 0);
  }
#pragma unroll
  for (int i = 0; i < 4; i++) {
    int row = m0 + wm * 64 + i * 16 + quad * 4;
#pragma unroll
    for (int j = 0; j < 4; j++) {
      int col = n0 + wn * 64 + j * 16 + l16;
      float bv = bias ? bias[col] : 0.f;
#pragma unroll
      for (int r = 0; r < 4; r++) {
        int gr = row + r;
        int orow = permute ? (gr % H_) * B_ + gr / H_ : gr;
        float v = acc[i][j][r] + bv;
        if (OUT_BF16)
          ((bf16*)Cout)[(size_t)orow * N + col] = __float2bfloat16(v);
        else
          ((float*)Cout)[(size_t)orow * N + col] = v;
      }
    }
  }
}

// ---- conv GEMM: A fp32 (converted in-register during staging), bf16 out,
// rows permuted (b*H+t) -> (t*B+b). Deletes the separate cvt pass.
__device__ inline short8 cvt8(float4 a, float4 b) {
  union { bf16 h[8]; short8 s; } u;
  u.h[0] = __float2bfloat16(a.x); u.h[1] = __float2bfloat16(a.y);
  u.h[2] = __float2bfloat16(a.z); u.h[3] = __float2bfloat16(a.w);
  u.h[4] = __float2bfloat16(b.x); u.h[5] = __float2bfloat16(b.y);
  u.h[6] = __float2bfloat16(b.z); u.h[7] = __float2bfloat16(b.w);
  return u.s;
}
__global__ __launch_bounds__(256) void gemm_a32_bt(const float* __restrict__ A,
                                                   const bf16* __restrict__ BT,
                                                   const float* __restrict__ bias,
                                                   bf16* __restrict__ Cout,
                                                   int M, int N, int K) {
  __shared__ short As[128 * 40];
  __shared__ short Bs[128 * 40];
  int tid  = threadIdx.x;
  int wave = tid >> 6, lane = tid & 63;
  int wm = wave >> 1, wn = wave & 1;
  int quad = lane >> 4, l16 = lane & 15;
  int m0 = blockIdx.y * 128, n0 = blockIdx.x * 128;

  floatx4 acc[4][4];
#pragma unroll
  for (int i = 0; i < 4; i++)
#pragma unroll
    for (int j = 0; j < 4; j++) acc[i][j] = (floatx4){0.f, 0.f, 0.f, 0.f};

  int r0 = tid >> 2;
  int c0 = (tid & 3) * 8;

  for (int k0 = 0; k0 < K; k0 += 32) {
    const float* ap0 = A + (size_t)(m0 + r0)      * K + k0 + c0;
    const float* ap1 = A + (size_t)(m0 + r0 + 64) * K + k0 + c0;
    float4 fa0 = *(const float4*)ap0, fa1 = *(const float4*)(ap0 + 4);
    float4 fb0 = *(const float4*)ap1, fb1 = *(const float4*)(ap1 + 4);
    short8 a0 = cvt8(fa0, fa1);
    short8 a1 = cvt8(fb0, fb1);
    short8 b0 = *(const short8*)(BT + (size_t)(n0 + r0)      * K + k0 + c0);
    short8 b1 = *(const short8*)(BT + (size_t)(n0 + r0 + 64) * K + k0 + c0);
    __syncthreads();
    *(short8*)(&As[r0 * 40 + c0])        = a0;
    *(short8*)(&As[(r0 + 64) * 40 + c0]) = a1;
    *(short8*)(&Bs[r0 * 40 + c0])        = b0;
    *(short8*)(&Bs[(r0 + 64) * 40 + c0]) = b1;
    __syncthreads();
    short8 af[4], bfr[4];
#pragma unroll
    for (int i = 0; i < 4; i++)
      af[i] = *(const short8*)(&As[(wm * 64 + i * 16 + l16) * 40 + quad * 8]);
#pragma unroll
    for (int j = 0; j < 4; j++)
      bfr[j] = *(const short8*)(&Bs[(wn * 64 + j * 16 + l16) * 40 + quad * 8]);
#pragma unroll
    for (int i = 0; i < 4; i++)
#pragma unroll
      for (int j = 0; j < 4; j++)
        acc[i][j] = __builtin_amdgcn_mfma_f32_16x16x32_bf16(af[i], bfr[j],
                                                            acc[i][j], 0, 0, 0);
  }
#pragma unroll
  for (int i = 0; i < 4; i++) {
    int row = m0 + wm * 64 + i * 16 + quad * 4;
#pragma unroll
    for (int j = 0; j < 4; j++) {
      int col = n0 + wn * 64 + j * 16 + l16;
      float bv = bias[col];
#pragma unroll
      for (int r = 0; r < 4; r++) {
        int gr = row + r;
        int orow = (gr % H_) * B_ + gr / H_;   // (b*H+t) -> (t*B+b)
        Cout[(size_t)orow * N + col] = __float2bfloat16(acc[i][j][r] + bv);
      }
    }
  }
}

// ---------------- persistent LSTM recurrence (all 192 steps) ----------------
// 64 WGs x 256 thr. WG g owns n in [g*8,g*8+8) -> 32 gate cols {gate*512+n}.
// Weights LDS-resident. c in registers. h ring (fresh addresses -> cached
// consumer loads are safe). Producer h stores: relaxed agent-scope (ack at
// coherent Infinity Cache, drained by the pre-arrival syncthreads).
// Barrier: parallel done-stores + single aggregator (WG0 wave0 ballot-polls
// 64 words = 256B/sweep) + flag broadcast. No RMW chain, no poll storm.
__global__ __launch_bounds__(256) void lstm_persist(
    const bf16* __restrict__ rkT,   // [2048,512] recurrent (encoder)
    const bf16* __restrict__ wcT,   // [2048,512] k+rk (decoder)
    const float* __restrict__ bvec, // [2048]
    const float* __restrict__ xk,   // [H*B, 2048] fp32, rows t*B+b
    bf16* __restrict__ hring,       // [(TSTEPS+1)*B*N]; buffer 0 zeroed
    bf16* __restrict__ preds,       // [B,P,N]
    unsigned* __restrict__ done,    // [TSTEPS*NWG] zeroed
    unsigned* __restrict__ flag) {  // [TSTEPS] zeroed
  __shared__ short Wenc[32][520];
  __shared__ short Wdec[32][520];
  __shared__ float zs[32][33];
  __shared__ bf16  hstage[32][8];

  int tid  = threadIdx.x;
  int bid  = blockIdx.x;
  int wave = tid >> 6, lane = tid & 63;
  int tm = wave >> 1, tn = wave & 1;
  int quad = lane >> 4, l16 = lane & 15;
  int n0 = bid * 8;
  int lc   = tn * 16 + l16;                     // local col 0..31
  int gcol = ((lc >> 3) << 9) + n0 + (lc & 7);  // gate*512 + n
  int brow = tm * 16 + quad * 4;

  for (int idx = tid; idx < 32 * 64; idx += 256) {
    int r = idx >> 6, ck = (idx & 63) << 3;
    int grow = ((r >> 3) << 9) + n0 + (r & 7);
    *(short8*)&Wenc[r][ck] = *(const short8*)(rkT + (size_t)grow * 512 + ck);
    *(short8*)&Wdec[r][ck] = *(const short8*)(wcT + (size_t)grow * 512 + ck);
  }
  float bias_r = bvec[gcol];
  int b = tid >> 3, j = tid & 7;
  int nn = n0 + j;
  float c_reg = 0.f;

  // prefetch xk for t=0
  float xkv[4];
  {
    const float* xp = xk + (size_t)brow * G4N + gcol;
#pragma unroll
    for (int r = 0; r < 4; ++r) xkv[r] = xp[(size_t)r * G4N];
  }
  __syncthreads();

  for (int t = 0; t < TSTEPS; ++t) {
    const bf16* h_in  = hring + (size_t)t * HSZ;   // fresh address: cacheable
    bf16*       h_out = hring + (size_t)(t + 1) * HSZ;
    const short(*Ws)[520] = (t < H_) ? Wenc : Wdec;

    floatx4 acc0 = (floatx4){0.f, 0.f, 0.f, 0.f};
    floatx4 acc1 = (floatx4){0.f, 0.f, 0.f, 0.f};
    const bf16*  ap = h_in + (size_t)(tm * 16 + l16) * 512 + quad * 8;
    const short* bp = &Ws[lc][quad * 8];
#pragma unroll
    for (int k0 = 0; k0 < 512; k0 += 64) {
      short8 av0 = *(const short8*)(ap + k0);       // normal load: L2-shared
      short8 av1 = *(const short8*)(ap + k0 + 32);
      short8 bv0 = *(const short8*)(bp + k0);
      short8 bv1 = *(const short8*)(bp + k0 + 32);
      acc0 = __builtin_amdgcn_mfma_f32_16x16x32_bf16(av0, bv0, acc0, 0, 0, 0);
      acc1 = __builtin_amdgcn_mfma_f32_16x16x32_bf16(av1, bv1, acc1, 0, 0, 0);
    }
    floatx4 acc = acc0 + acc1;
#pragma unroll
    for (int r = 0; r < 4; ++r)
      zs[brow + r][lc] = acc[r] + bias_r + xkv[r];

    // prefetch next step's xk (consumed after the barrier)
    float xn[4] = {0.f, 0.f, 0.f, 0.f};
    if (t + 1 < H_) {
      const float* xp = xk + (size_t)((t + 1) * B_ + brow) * G4N + gcol;
#pragma unroll
      for (int r = 0; r < 4; ++r) xn[r] = xp[(size_t)r * G4N];
    }
    __syncthreads();

    // ---- gates ----
    float zi = zs[b][j], zf = zs[b][8 + j], zg = zs[b][16 + j], zo = zs[b][24 + j];
    float ig = 1.f / (1.f + __expf(-zi));
    float fg = 1.f / (1.f + __expf(-zf));
    float gg = tanhf(zg);
    float og = 1.f / (1.f + __expf(-zo));
    c_reg = fg * c_reg + ig * gg;
    float hn = og * tanhf(c_reg);
    hstage[b][j] = __float2bfloat16(hn);
    if (t >= H_)
      preds[(size_t)b * (P_ * N_) + (t - H_) * N_ + nn] = __float2bfloat16(hn);
    __syncthreads();

    // ---- packed h_out stores: 64 threads x 8B, L2-bypass to coherent L3 ----
    if (tid < 64) {
      int bb = tid >> 1, f4 = (tid & 1) * 4;
      unsigned long long v = *(const unsigned long long*)&hstage[bb][f4];
      __hip_atomic_store((unsigned long long*)(h_out + bb * 512 + n0 + f4), v,
                         __ATOMIC_RELAXED, __HIP_MEMORY_SCOPE_AGENT);
    }
    // each wave's s_waitcnt vmcnt(0) before s_barrier acks its h stores at
    // the coherent point; the barrier orders all waves before arrival below.
    __syncthreads();

    // ---- aggregator barrier: parallel arrival, one sweeper, flag bcast ----
    if (tid == 0)
      __hip_atomic_store(&done[(size_t)t * NWG + bid], 1u, __ATOMIC_RELAXED,
                         __HIP_MEMORY_SCOPE_AGENT);
    if (bid == 0) {
      if (tid < 64) {
        const unsigned* dp = done + (size_t)t * NWG;
        for (;;) {
          unsigned v = __hip_atomic_load(dp + tid, __ATOMIC_RELAXED,
                                         __HIP_MEMORY_SCOPE_AGENT);
          if (__builtin_popcountll(__ballot(v != 0)) == 64) break;
          __builtin_amdgcn_s_sleep(1);
        }
        if (tid == 0)
          __hip_atomic_store(&flag[t], 1u, __ATOMIC_RELAXED,
                             __HIP_MEMORY_SCOPE_AGENT);
      }
    } else if (tid == 0) {
      while (!__hip_atomic_load(&flag[t], __ATOMIC_RELAXED,
                                __HIP_MEMORY_SCOPE_AGENT))
        __builtin_amdgcn_s_sleep(1);
    }
    __builtin_amdgcn_fence(__ATOMIC_ACQUIRE, "workgroup");  // order pin only
    __syncthreads();
#pragma unroll
    for (int r = 0; r < 4; ++r) xkv[r] = xn[r];
  }
}

extern "C" void kernel_launch(void* const* d_in, const int* in_sizes, int n_in,
                              void* d_out, int out_size, void* d_ws, size_t ws_size,
                              hipStream_t stream) {
  const float* x       = (const float*)d_in[0];
  const float* conv_w  = (const float*)d_in[1];
  const float* conv_b  = (const float*)d_in[2];
  const float* lstm_k  = (const float*)d_in[3];
  const float* lstm_rk = (const float*)d_in[4];
  const float* lstm_b  = (const float*)d_in[5];
  const float* dense_w = (const float*)d_in[6];
  const float* dense_b = (const float*)d_in[7];
  float* out = (float*)d_out;

  char* p = (char*)d_ws;
  auto carve = [&](size_t bytes) {
    char* r = p;
    p += (bytes + 255) & ~(size_t)255;
    return r;
  };
  bf16*  xr    = (bf16*)carve((size_t)M1 * N_ * 2);    // rows t*B+b
  float* xk    = (float*)carve((size_t)M1 * G4N * 4);  // rows t*B+b
  bf16*  cwT   = (bf16*)carve((size_t)N_ * NF_ * 2);
  bf16*  kT    = (bf16*)carve((size_t)G4N * N_ * 2);
  bf16*  rkT   = (bf16*)carve((size_t)G4N * N_ * 2);
  bf16*  wcT   = (bf16*)carve((size_t)G4N * N_ * 2);
  bf16*  dwT   = (bf16*)carve((size_t)N_ * N_ * 2);
  bf16*  preds = (bf16*)carve((size_t)B_ * P_ * N_ * 2);
  bf16*  hring = (bf16*)carve((size_t)(TSTEPS + 1) * HSZ * 2);  // 6.3 MB
  unsigned* done = (unsigned*)carve((size_t)TSTEPS * NWG * 4);  // 48 KB
  unsigned* flag = (unsigned*)carve((size_t)TSTEPS * 4);

  dim3 tb(32, 8);
  transpose_cvt<<<dim3(N_ / 32, NF_ / 32), tb, 0, stream>>>(conv_w, cwT, NF_, N_);
  transpose_krk<<<dim3(G4N / 32, N_ / 32), tb, 0, stream>>>(lstm_k, lstm_rk,
                                                            kT, rkT, wcT);
  transpose_cvt<<<dim3(N_ / 32, N_ / 32), tb, 0, stream>>>(dense_w, dwT, N_, N_);
  hipMemsetAsync(hring, 0, (size_t)HSZ * 2, stream);   // h[0] = 0
  hipMemsetAsync(done, 0, (size_t)TSTEPS * NWG * 4, stream);
  hipMemsetAsync(flag, 0, (size_t)TSTEPS * 4, stream);

  // xr = x(f32) @ conv_w + conv_b, fused cvt, rows permuted -> (t*B+b)
  gemm_a32_bt<<<dim3(N_ / 128, M1 / 128), 256, 0, stream>>>(x, cwT, conv_b, xr,
                                                            M1, N_, NF_);
  // xk = xr @ lstm_k -> fp32 (row order preserved: t*B+b)
  gemm_bt<false><<<dim3(G4N / 128, M1 / 128), 256, 0, stream>>>(xr, kT, nullptr,
                                                                xk, M1, G4N, N_, 0);

  lstm_persist<<<NWG, 256, 0, stream>>>(rkT, wcT, lstm_b, xk, hring, preds,
                                        done, flag);

  // out = preds @ dense_w + dense_b
  gemm_bt<false><<<dim3(N_ / 128, (B_ * P_) / 128), 256, 0, stream>>>(
      preds, dwT, dense_b, out, B_ * P_, N_, N_, 0);
}